// Round 4
// baseline (1047.234 us; speedup 1.0000x reference)
//
#include <hip/hip_runtime.h>
#include <hip/hip_bf16.h>

#define NEG_SLOPE 0.2f
#define STATS_SPLIT 50

// ---------------------------------------------------------------------------
// K1: h = input @ W_fc  (N x 128) @ (128 x 128), fused el/er epilogue.
// 64-row tile, 256 threads, 4x8 acc/thread (cols tx*4.. and 64+tx*4..).
// ---------------------------------------------------------------------------
__global__ __launch_bounds__(256, 4) void fc_gemm_kernel(
    const float* __restrict__ A, const float* __restrict__ W,
    const float* __restrict__ attn_l, const float* __restrict__ attn_r,
    float* __restrict__ h, float* __restrict__ el, float* __restrict__ er,
    int n)
{
    __shared__ float As[32][68];   // k-major: As[k][row]
    __shared__ float Bs[32][132];  // k-major: Bs[k][col]
    const int tid = threadIdx.x;
    const int tx = tid & 15;       // two col-quads: tx*4, 64+tx*4
    const int ty = tid >> 4;       // rows ty*4 .. ty*4+3
    const int rowBase = blockIdx.x * 64;

    float acc[4][8];
#pragma unroll
    for (int i = 0; i < 4; ++i)
#pragma unroll
        for (int j = 0; j < 8; ++j) acc[i][j] = 0.f;

    for (int ci = 0; ci < 4; ++ci) {
        const int kc = ci * 32;
        // stage A: 64 rows x 32 k  (512 float4, 2 per thread)
#pragma unroll
        for (int it = 0; it < 2; ++it) {
            const int flat = it * 256 + tid;
            const int q = flat & 7;        // k-quad
            const int r = flat >> 3;       // row 0..63
            int row = rowBase + r;
            if (row >= n) row = n - 1;
            const float4 v = *(const float4*)&A[(long long)row * 128 + kc + q * 4];
            As[q * 4 + 0][r] = v.x;
            As[q * 4 + 1][r] = v.y;
            As[q * 4 + 2][r] = v.z;
            As[q * 4 + 3][r] = v.w;
        }
        // stage B: 32 k x 128 cols (1024 float4, 4 per thread)
#pragma unroll
        for (int it = 0; it < 4; ++it) {
            const int flat = it * 256 + tid;
            const int k = flat >> 5;
            const int c4 = flat & 31;
            *(float4*)&Bs[k][c4 * 4] =
                *(const float4*)&W[(long long)(kc + k) * 128 + c4 * 4];
        }
        __syncthreads();

#pragma unroll
        for (int k = 0; k < 32; ++k) {
            const float4 a  = *(const float4*)&As[k][ty * 4];
            const float4 b0 = *(const float4*)&Bs[k][tx * 4];
            const float4 b1 = *(const float4*)&Bs[k][64 + tx * 4];
            const float ar[4] = {a.x, a.y, a.z, a.w};
            const float br[8] = {b0.x, b0.y, b0.z, b0.w, b1.x, b1.y, b1.z, b1.w};
#pragma unroll
            for (int i = 0; i < 4; ++i)
#pragma unroll
                for (int j = 0; j < 8; ++j) acc[i][j] += ar[i] * br[j];
        }
        __syncthreads();
    }

    // epilogue: write h, fused el/er (head h0 = tx>>2 over cols tx*4..; head 4+h0)
    const float4 alA = *(const float4*)&attn_l[tx * 4];
    const float4 alB = *(const float4*)&attn_l[64 + tx * 4];
    const float4 arA = *(const float4*)&attn_r[tx * 4];
    const float4 arB = *(const float4*)&attn_r[64 + tx * 4];
#pragma unroll
    for (int i = 0; i < 4; ++i) {
        const int row = rowBase + ty * 4 + i;
        if (row >= n) break;
        const long long off = (long long)row * 128;
        float4 o0 = {acc[i][0], acc[i][1], acc[i][2], acc[i][3]};
        float4 o1 = {acc[i][4], acc[i][5], acc[i][6], acc[i][7]};
        *(float4*)&h[off + tx * 4] = o0;
        *(float4*)&h[off + 64 + tx * 4] = o1;
        float l0 = o0.x * alA.x + o0.y * alA.y + o0.z * alA.z + o0.w * alA.w;
        float l1 = o1.x * alB.x + o1.y * alB.y + o1.z * alB.z + o1.w * alB.w;
        float r0 = o0.x * arA.x + o0.y * arA.y + o0.z * arA.z + o0.w * arA.w;
        float r1 = o1.x * arB.x + o1.y * arB.y + o1.z * arB.z + o1.w * arB.w;
#pragma unroll
        for (int offx = 1; offx <= 2; offx <<= 1) {
            l0 += __shfl_xor(l0, offx, 64);
            l1 += __shfl_xor(l1, offx, 64);
            r0 += __shfl_xor(r0, offx, 64);
            r1 += __shfl_xor(r1, offx, 64);
        }
        if ((tx & 3) == 0) {
            const int hd = tx >> 2;
            el[(long long)row * 8 + hd] = l0;
            el[(long long)row * 8 + 4 + hd] = l1;
            er[(long long)row * 8 + hd] = r0;
            er[(long long)row * 8 + 4 + hd] = r1;
        }
    }
}

// ---------------------------------------------------------------------------
// CSR build: histogram -> 2-level exclusive scan -> scatter src ids by dst.
// ---------------------------------------------------------------------------
__global__ __launch_bounds__(256) void hist_kernel(
    const int* __restrict__ dst, int* __restrict__ deg, int E)
{
    const int i = blockIdx.x * 256 + threadIdx.x;
    if (i < E) atomicAdd(&deg[dst[i]], 1);
}

__global__ __launch_bounds__(256) void scan1_kernel(
    const int* __restrict__ deg, int* __restrict__ row,
    int* __restrict__ blockSums, int n)
{
    __shared__ int sdata[256];
    const int t = threadIdx.x;
    const int base = blockIdx.x * 1024 + t * 4;
    int v[4];
    int tot = 0;
#pragma unroll
    for (int j = 0; j < 4; ++j) {
        v[j] = (base + j < n) ? deg[base + j] : 0;
        tot += v[j];
    }
    sdata[t] = tot;
    __syncthreads();
    for (int off = 1; off < 256; off <<= 1) {
        const int x = (t >= off) ? sdata[t - off] : 0;
        __syncthreads();
        sdata[t] += x;
        __syncthreads();
    }
    if (t == 255) blockSums[blockIdx.x] = sdata[255];
    int run = sdata[t] - tot;
#pragma unroll
    for (int j = 0; j < 4; ++j) {
        if (base + j < n) row[base + j] = run;
        run += v[j];
    }
}

__global__ __launch_bounds__(128) void scan2_kernel(
    int* __restrict__ blockSums, int nb)
{
    __shared__ int sdata[128];
    const int t = threadIdx.x;
    const int v = (t < nb) ? blockSums[t] : 0;
    sdata[t] = v;
    __syncthreads();
    for (int off = 1; off < 128; off <<= 1) {
        const int x = (t >= off) ? sdata[t - off] : 0;
        __syncthreads();
        sdata[t] += x;
        __syncthreads();
    }
    if (t < nb) blockSums[t] = sdata[t] - v;
}

__global__ __launch_bounds__(256) void scan3_kernel(
    int* __restrict__ row, int* __restrict__ cursor,
    const int* __restrict__ blockSums, int n, int E)
{
    const int i = blockIdx.x * 256 + threadIdx.x;
    if (i == 0) row[n] = E;
    if (i >= n) return;
    const int r = row[i] + blockSums[i >> 10];
    row[i] = r;
    cursor[i] = r;
}

__global__ __launch_bounds__(256) void scatter_kernel(
    const int* __restrict__ src, const int* __restrict__ dst,
    int* __restrict__ cursor, int* __restrict__ srcs, int E)
{
    const int i = blockIdx.x * 256 + threadIdx.x;
    if (i >= E) return;
    const int pos = atomicAdd(&cursor[dst[i]], 1);
    srcs[pos] = src[i];
}

// ---------------------------------------------------------------------------
// K3: aggregate. One wave per dst node, 2 features/lane, local softmax,
// no atomics.
// ---------------------------------------------------------------------------
__global__ __launch_bounds__(256) void aggregate_kernel(
    const float* __restrict__ el, const float* __restrict__ er,
    const float* __restrict__ h, const int* __restrict__ row,
    const int* __restrict__ srcs, float* __restrict__ rst, int n)
{
    const int wave = blockIdx.x * 4 + (threadIdx.x >> 6);
    const int lane = threadIdx.x & 63;
    if (wave >= n) return;
    const int d = wave;
    const int start = row[d], end = row[d + 1];
    const int hd0 = lane >> 4;
    const float er0 = er[(long long)d * 8 + hd0];
    const float er1 = er[(long long)d * 8 + hd0 + 4];

    float acc0 = 0.f, acc1 = 0.f, den0 = 0.f, den1 = 0.f;
    for (int p = start; p < end; ++p) {
        const int s = srcs[p];
        float e0 = el[(long long)s * 8 + hd0] + er0;
        float e1 = el[(long long)s * 8 + hd0 + 4] + er1;
        e0 = e0 >= 0.f ? e0 : NEG_SLOPE * e0;
        e1 = e1 >= 0.f ? e1 : NEG_SLOPE * e1;
        const float w0 = __expf(e0);
        const float w1 = __expf(e1);
        den0 += w0; den1 += w1;
        acc0 += w0 * h[(long long)s * 128 + lane];
        acc1 += w1 * h[(long long)s * 128 + 64 + lane];
    }
    const float r0 = (end > start) ? acc0 / den0 : 0.f;
    const float r1 = (end > start) ? acc1 / den1 : 0.f;
    rst[(long long)d * 128 + lane] = r0;
    rst[(long long)d * 128 + 64 + lane] = r1;
}

// ---------------------------------------------------------------------------
// K4: GCNII combine, K=256 (concat(rst+bias, h0)). 64-row tile. The r-term
// ((1-th)((1-a)(rst+bias)+a*h0)) is captured IN-REGISTER from the staged LDS
// fragments during the matching k-chunk — no epilogue re-read of rst/h0.
// ---------------------------------------------------------------------------
__global__ __launch_bounds__(256, 4) void combine_gemm_kernel(
    const float* __restrict__ rst, const float* __restrict__ gat_bias,
    const float* __restrict__ h0, const float* __restrict__ input,
    const float* __restrict__ W, const int* __restrict__ l_p,
    const float* __restrict__ lamda_p, const float* __restrict__ alpha_p,
    float* __restrict__ x, int n)
{
    __shared__ float As[32][68];
    __shared__ float Bs[32][132];
    const int tid = threadIdx.x;
    const int tx = tid & 15;
    const int ty = tid >> 4;
    const int rowBase = blockIdx.x * 64;

    const float alpha = alpha_p[0];
    const float theta = fminf(1.0f, logf(lamda_p[0] / (float)l_p[0] + 1.0f));
    const float c1 = (1.f - theta) * (1.f - alpha);  // scale for rst+bias
    const float c2 = (1.f - theta) * alpha;          // scale for h0

    float acc[4][8];
    float E[4][8];
#pragma unroll
    for (int i = 0; i < 4; ++i)
#pragma unroll
        for (int j = 0; j < 8; ++j) { acc[i][j] = 0.f; E[i][j] = 0.f; }

    const int t3 = tx >> 3;      // chunk selector base
    const int t7 = tx & 7;       // within-chunk k-quad

    for (int ci = 0; ci < 8; ++ci) {
        const int kc = ci * 32;
        const int koff = kc & 127;
        const bool first = ci < 4;
#pragma unroll
        for (int it = 0; it < 2; ++it) {
            const int flat = it * 256 + tid;
            const int q = flat & 7;
            const int r = flat >> 3;
            int row = rowBase + r;
            if (row >= n) row = n - 1;
            float4 v;
            if (first) {
                v = *(const float4*)&rst[(long long)row * 128 + koff + q * 4];
                const float4 b = *(const float4*)&gat_bias[koff + q * 4];
                v.x += b.x; v.y += b.y; v.z += b.z; v.w += b.w;
            } else {
                v = *(const float4*)&h0[(long long)row * 128 + koff + q * 4];
            }
            As[q * 4 + 0][r] = v.x;
            As[q * 4 + 1][r] = v.y;
            As[q * 4 + 2][r] = v.z;
            As[q * 4 + 3][r] = v.w;
        }
#pragma unroll
        for (int it = 0; it < 4; ++it) {
            const int flat = it * 256 + tid;
            const int k = flat >> 5;
            const int c4 = flat & 31;
            *(float4*)&Bs[k][c4 * 4] =
                *(const float4*)&W[(long long)(kc + k) * 128 + c4 * 4];
        }
        __syncthreads();

        // capture scales: group A = cols tx*4+j (support col c = tx*4+j for rst
        // at chunk t3, c+128 for h0 at chunk 4+t3); group B = cols 64+tx*4+j.
        const float sA = (ci == t3) ? c1 : ((ci == 4 + t3) ? c2 : 0.f);
        const float sB = (ci == 2 + t3) ? c1 : ((ci == 6 + t3) ? c2 : 0.f);

#pragma unroll
        for (int k = 0; k < 32; ++k) {
            const float4 a  = *(const float4*)&As[k][ty * 4];
            const float4 b0 = *(const float4*)&Bs[k][tx * 4];
            const float4 b1 = *(const float4*)&Bs[k][64 + tx * 4];
            const float ar[4] = {a.x, a.y, a.z, a.w};
            const float br[8] = {b0.x, b0.y, b0.z, b0.w, b1.x, b1.y, b1.z, b1.w};
#pragma unroll
            for (int i = 0; i < 4; ++i)
#pragma unroll
                for (int j = 0; j < 8; ++j) acc[i][j] += ar[i] * br[j];
            // in-register capture of support values at this thread's out cols
            const bool hit = ((k >> 2) == t7);
            const float sa = hit ? sA : 0.f;
            const float sb = hit ? sB : 0.f;
#pragma unroll
            for (int i = 0; i < 4; ++i) {
                E[i][k & 3] += sa * ar[i];
                E[i][4 + (k & 3)] += sb * ar[i];
            }
        }
        __syncthreads();
    }

#pragma unroll
    for (int i = 0; i < 4; ++i) {
        const int row = rowBase + ty * 4 + i;
        if (row >= n) break;
        const long long off = (long long)row * 128;
        const float4 in0 = *(const float4*)&input[off + tx * 4];
        const float4 in1 = *(const float4*)&input[off + 64 + tx * 4];
        float4 o0, o1;
        o0.x = theta * acc[i][0] + E[i][0] + in0.x;
        o0.y = theta * acc[i][1] + E[i][1] + in0.y;
        o0.z = theta * acc[i][2] + E[i][2] + in0.z;
        o0.w = theta * acc[i][3] + E[i][3] + in0.w;
        o1.x = theta * acc[i][4] + E[i][4] + in1.x;
        o1.y = theta * acc[i][5] + E[i][5] + in1.y;
        o1.z = theta * acc[i][6] + E[i][6] + in1.z;
        o1.w = theta * acc[i][7] + E[i][7] + in1.w;
        *(float4*)&x[off + tx * 4] = o0;
        *(float4*)&x[off + 64 + tx * 4] = o1;
    }
}

// ---------------------------------------------------------------------------
// K5: per-subgraph partial sums (split over nodes, atomics into (B,128)).
// ---------------------------------------------------------------------------
__global__ __launch_bounds__(128) void stats_kernel(
    const float* __restrict__ x, const int* __restrict__ cums,
    float* __restrict__ sums, float* __restrict__ sumsq)
{
    const int b = blockIdx.x / STATS_SPLIT;
    const int part = blockIdx.x % STATS_SPLIT;
    const int tid = threadIdx.x;
    const int start = cums[b], end = cums[b + 1];
    float s = 0.f, s2 = 0.f;
    for (int node = start + part; node < end; node += STATS_SPLIT) {
        const float v = x[(long long)node * 128 + tid];
        s += v;
        s2 += v * v;
    }
    atomicAdd(&sums[b * 128 + tid], s);
    atomicAdd(&sumsq[b * 128 + tid], s2);
}

__global__ __launch_bounds__(128) void finalize_stats_kernel(
    const int* __restrict__ cums, float* __restrict__ sums,
    float* __restrict__ sumsq)
{
    const int b = blockIdx.x;
    const int tid = threadIdx.x;
    const float cnt = (float)(cums[b + 1] - cums[b]);
    const float s = sums[b * 128 + tid];
    const float s2 = sumsq[b * 128 + tid];
    const float mean = s / cnt;
    float var = (s2 - s * mean) / (cnt - 1.f);
    var = fmaxf(var, 0.f);
    sums[b * 128 + tid] = mean;
    sumsq[b * 128 + tid] = 1.f / (sqrtf(var) + 1e-5f);
}

__global__ __launch_bounds__(256) void norm_kernel(
    const float* __restrict__ x, const float* __restrict__ mean,
    const float* __restrict__ istd, const int* __restrict__ cums, int nb,
    const float* __restrict__ gamma, const float* __restrict__ beta,
    float* __restrict__ out, int n)
{
    const long long gid = (long long)blockIdx.x * 256 + threadIdx.x;
    const int node = (int)(gid >> 5);
    if (node >= n) return;
    const int f4 = (int)(gid & 31);
    int lo = 0, hi = nb;
    while (hi - lo > 1) {
        const int mid = (lo + hi) >> 1;
        if (cums[mid] <= node) lo = mid; else hi = mid;
    }
    const float4 m = *(const float4*)&mean[lo * 128 + f4 * 4];
    const float4 is = *(const float4*)&istd[lo * 128 + f4 * 4];
    const float4 g = *(const float4*)&gamma[f4 * 4];
    const float4 bt = *(const float4*)&beta[f4 * 4];
    const float4 v = *(const float4*)&x[(long long)node * 128 + f4 * 4];
    float4 o;
    o.x = g.x * ((v.x - m.x) * is.x) + bt.x;
    o.y = g.y * ((v.y - m.y) * is.y) + bt.y;
    o.z = g.z * ((v.z - m.z) * is.z) + bt.z;
    o.w = g.w * ((v.w - m.w) * is.w) + bt.w;
    *(float4*)&out[(long long)node * 128 + f4 * 4] = o;
}

// ---------------------------------------------------------------------------
extern "C" void kernel_launch(void* const* d_in, const int* in_sizes, int n_in,
                              void* d_out, int out_size, void* d_ws, size_t ws_size,
                              hipStream_t stream) {
    const float* input   = (const float*)d_in[0];
    const float* h0      = (const float*)d_in[1];
    const int*   src     = (const int*)d_in[2];
    const int*   dst     = (const int*)d_in[3];
    const int*   cums    = (const int*)d_in[4];
    const int*   l_p     = (const int*)d_in[5];
    const float* lamda_p = (const float*)d_in[6];
    const float* alpha_p = (const float*)d_in[7];
    const float* W_fc    = (const float*)d_in[8];
    const float* attn_l  = (const float*)d_in[9];
    const float* attn_r  = (const float*)d_in[10];
    const float* gat_bias= (const float*)d_in[11];
    const float* W_comb  = (const float*)d_in[12];
    const float* gamma   = (const float*)d_in[13];
    const float* beta    = (const float*)d_in[14];

    const int n  = in_sizes[0] / 128;
    const int E  = in_sizes[2];
    const int nb = in_sizes[4] - 1;
    float* out = (float*)d_out;

    // workspace layout
    char* ws = (char*)d_ws;
    size_t o = 0;
    float* h        = (float*)(ws + o); o += (size_t)n * 128 * 4;
    float* el       = (float*)(ws + o); o += (size_t)n * 8 * 4;
    float* er       = (float*)(ws + o); o += (size_t)n * 8 * 4;
    float* rst      = (float*)(ws + o); o += (size_t)n * 128 * 4;
    float* sums     = (float*)(ws + o); o += (size_t)nb * 128 * 4;
    float* sumsq    = (float*)(ws + o); o += (size_t)nb * 128 * 4;
    int* deg        = (int*)(ws + o);   o += (size_t)n * 4;
    int* row_ptr    = (int*)(ws + o);   o += (size_t)(n + 1) * 4;
    int* cursor     = (int*)(ws + o);   o += (size_t)n * 4;
    int* blockSums  = (int*)(ws + o);   o += 128 * 4;
    int* srcs       = (int*)(ws + o);   o += (size_t)E * 4;

    hipMemsetAsync(deg, 0, (size_t)n * 4, stream);
    hipMemsetAsync(sums, 0, (size_t)nb * 128 * 4 * 2, stream);

    // --- CSR build ---
    hist_kernel<<<(E + 255) / 256, 256, 0, stream>>>(dst, deg, E);
    const int nblk1 = (n + 1023) / 1024;
    scan1_kernel<<<nblk1, 256, 0, stream>>>(deg, row_ptr, blockSums, n);
    scan2_kernel<<<1, 128, 0, stream>>>(blockSums, nblk1);
    scan3_kernel<<<(n + 255) / 256, 256, 0, stream>>>(row_ptr, cursor, blockSums, n, E);
    scatter_kernel<<<(E + 255) / 256, 256, 0, stream>>>(src, dst, cursor, srcs, E);

    // --- dense pipeline ---
    const int gemm_grid = (n + 63) / 64;
    fc_gemm_kernel<<<gemm_grid, 256, 0, stream>>>(
        input, W_fc, attn_l, attn_r, h, el, er, n);

    aggregate_kernel<<<(n + 3) / 4, 256, 0, stream>>>(
        el, er, h, row_ptr, srcs, rst, n);

    combine_gemm_kernel<<<gemm_grid, 256, 0, stream>>>(
        rst, gat_bias, h0, input, W_comb, l_p, lamda_p, alpha_p, out, n);

    stats_kernel<<<nb * STATS_SPLIT, 128, 0, stream>>>(out, cums, sums, sumsq);
    finalize_stats_kernel<<<nb, 128, 0, stream>>>(cums, sums, sumsq);

    const long long norm_threads = (long long)n * 32;
    norm_kernel<<<(int)((norm_threads + 255) / 256), 256, 0, stream>>>(
        out, sums, sumsq, cums, nb, gamma, beta, out, n);
}

// Round 5
// 437.608 us; speedup vs baseline: 2.3931x; 2.3931x over previous
//
#include <hip/hip_runtime.h>
#include <hip/hip_bf16.h>

#define NEG_SLOPE 0.2f
#define STATS_SPLIT 50

// ---------------------------------------------------------------------------
// K1: h = input @ W_fc  (N x 128) @ (128 x 128), fused el/er epilogue.
// 128-row tile, 256 threads, 8x8 acc/thread, split cols (tx*4 and 64+tx*4).
// waves_per_eu(4,4): pin register budget to 128 VGPR -> no scratch spills.
// ---------------------------------------------------------------------------
__global__ __launch_bounds__(256)
__attribute__((amdgpu_waves_per_eu(4, 4)))
void fc_gemm_kernel(
    const float* __restrict__ A, const float* __restrict__ W,
    const float* __restrict__ attn_l, const float* __restrict__ attn_r,
    float* __restrict__ h, float* __restrict__ el, float* __restrict__ er,
    int n)
{
    __shared__ float As[32][132];  // k-major: As[k][row], 128 rows + pad
    __shared__ float Bs[32][132];  // k-major: Bs[k][col]
    const int tid = threadIdx.x;
    const int tx = tid & 15;       // col quads: tx*4 and 64+tx*4
    const int ty = tid >> 4;       // rows ty*8 .. ty*8+7
    const int rowBase = blockIdx.x * 128;

    float acc[8][8];
#pragma unroll
    for (int i = 0; i < 8; ++i)
#pragma unroll
        for (int j = 0; j < 8; ++j) acc[i][j] = 0.f;

    for (int ci = 0; ci < 4; ++ci) {
        const int kc = ci * 32;
        // stage A: 128 rows x 32 k (1024 float4, 4/thread), transposed store
#pragma unroll
        for (int it = 0; it < 4; ++it) {
            const int flat = it * 256 + tid;
            const int r = flat >> 3;       // row 0..127
            const int q = flat & 7;        // k-quad
            int row = rowBase + r;
            if (row >= n) row = n - 1;
            const float4 v = *(const float4*)&A[(long long)row * 128 + kc + q * 4];
            As[q * 4 + 0][r] = v.x;
            As[q * 4 + 1][r] = v.y;
            As[q * 4 + 2][r] = v.z;
            As[q * 4 + 3][r] = v.w;
        }
        // stage B: 32 k x 128 cols (1024 float4, 4/thread)
#pragma unroll
        for (int it = 0; it < 4; ++it) {
            const int flat = it * 256 + tid;
            const int k = flat >> 5;
            const int c4 = flat & 31;
            *(float4*)&Bs[k][c4 * 4] =
                *(const float4*)&W[(long long)(kc + k) * 128 + c4 * 4];
        }
        __syncthreads();

#pragma unroll
        for (int k = 0; k < 32; ++k) {
            const float4 a0 = *(const float4*)&As[k][ty * 8];
            const float4 a1 = *(const float4*)&As[k][ty * 8 + 4];
            const float4 b0 = *(const float4*)&Bs[k][tx * 4];
            const float4 b1 = *(const float4*)&Bs[k][64 + tx * 4];
            const float ar[8] = {a0.x, a0.y, a0.z, a0.w, a1.x, a1.y, a1.z, a1.w};
            const float br[8] = {b0.x, b0.y, b0.z, b0.w, b1.x, b1.y, b1.z, b1.w};
#pragma unroll
            for (int i = 0; i < 8; ++i)
#pragma unroll
                for (int j = 0; j < 8; ++j) acc[i][j] += ar[i] * br[j];
        }
        __syncthreads();
    }

    // epilogue: write h + fused el/er.
    // group A cols tx*4.. -> head tx>>2; group B cols 64+tx*4.. -> head 4+(tx>>2)
    const float4 alA = *(const float4*)&attn_l[tx * 4];
    const float4 alB = *(const float4*)&attn_l[64 + tx * 4];
    const float4 arA = *(const float4*)&attn_r[tx * 4];
    const float4 arB = *(const float4*)&attn_r[64 + tx * 4];
#pragma unroll
    for (int i = 0; i < 8; ++i) {
        const int row = rowBase + ty * 8 + i;
        if (row >= n) break;
        const long long off = (long long)row * 128;
        float4 o0 = {acc[i][0], acc[i][1], acc[i][2], acc[i][3]};
        float4 o1 = {acc[i][4], acc[i][5], acc[i][6], acc[i][7]};
        *(float4*)&h[off + tx * 4] = o0;
        *(float4*)&h[off + 64 + tx * 4] = o1;
        float l0 = o0.x * alA.x + o0.y * alA.y + o0.z * alA.z + o0.w * alA.w;
        float l1 = o1.x * alB.x + o1.y * alB.y + o1.z * alB.z + o1.w * alB.w;
        float r0 = o0.x * arA.x + o0.y * arA.y + o0.z * arA.z + o0.w * arA.w;
        float r1 = o1.x * arB.x + o1.y * arB.y + o1.z * arB.z + o1.w * arB.w;
#pragma unroll
        for (int offx = 1; offx <= 2; offx <<= 1) {
            l0 += __shfl_xor(l0, offx, 64);
            l1 += __shfl_xor(l1, offx, 64);
            r0 += __shfl_xor(r0, offx, 64);
            r1 += __shfl_xor(r1, offx, 64);
        }
        if ((tx & 3) == 0) {
            const int hd = tx >> 2;
            el[(long long)row * 8 + hd] = l0;
            el[(long long)row * 8 + 4 + hd] = l1;
            er[(long long)row * 8 + hd] = r0;
            er[(long long)row * 8 + 4 + hd] = r1;
        }
    }
}

// ---------------------------------------------------------------------------
// CSR build: histogram -> 2-level exclusive scan -> scatter src ids by dst.
// ---------------------------------------------------------------------------
__global__ __launch_bounds__(256) void hist_kernel(
    const int* __restrict__ dst, int* __restrict__ deg, int E)
{
    const int i = blockIdx.x * 256 + threadIdx.x;
    if (i < E) atomicAdd(&deg[dst[i]], 1);
}

__global__ __launch_bounds__(256) void scan1_kernel(
    const int* __restrict__ deg, int* __restrict__ row,
    int* __restrict__ blockSums, int n)
{
    __shared__ int sdata[256];
    const int t = threadIdx.x;
    const int base = blockIdx.x * 1024 + t * 4;
    int v[4];
    int tot = 0;
#pragma unroll
    for (int j = 0; j < 4; ++j) {
        v[j] = (base + j < n) ? deg[base + j] : 0;
        tot += v[j];
    }
    sdata[t] = tot;
    __syncthreads();
    for (int off = 1; off < 256; off <<= 1) {
        const int x = (t >= off) ? sdata[t - off] : 0;
        __syncthreads();
        sdata[t] += x;
        __syncthreads();
    }
    if (t == 255) blockSums[blockIdx.x] = sdata[255];
    int run = sdata[t] - tot;
#pragma unroll
    for (int j = 0; j < 4; ++j) {
        if (base + j < n) row[base + j] = run;
        run += v[j];
    }
}

__global__ __launch_bounds__(128) void scan2_kernel(
    int* __restrict__ blockSums, int nb)
{
    __shared__ int sdata[128];
    const int t = threadIdx.x;
    const int v = (t < nb) ? blockSums[t] : 0;
    sdata[t] = v;
    __syncthreads();
    for (int off = 1; off < 128; off <<= 1) {
        const int x = (t >= off) ? sdata[t - off] : 0;
        __syncthreads();
        sdata[t] += x;
        __syncthreads();
    }
    if (t < nb) blockSums[t] = sdata[t] - v;
}

__global__ __launch_bounds__(256) void scan3_kernel(
    int* __restrict__ row, int* __restrict__ cursor,
    const int* __restrict__ blockSums, int n, int E)
{
    const int i = blockIdx.x * 256 + threadIdx.x;
    if (i == 0) row[n] = E;
    if (i >= n) return;
    const int r = row[i] + blockSums[i >> 10];
    row[i] = r;
    cursor[i] = r;
}

__global__ __launch_bounds__(256) void scatter_kernel(
    const int* __restrict__ src, const int* __restrict__ dst,
    int* __restrict__ cursor, int* __restrict__ srcs, int E)
{
    const int i = blockIdx.x * 256 + threadIdx.x;
    if (i >= E) return;
    const int pos = atomicAdd(&cursor[dst[i]], 1);
    srcs[pos] = src[i];
}

// ---------------------------------------------------------------------------
// K3: aggregate. One wave per dst node, 2 features/lane, local softmax,
// no atomics.
// ---------------------------------------------------------------------------
__global__ __launch_bounds__(256) void aggregate_kernel(
    const float* __restrict__ el, const float* __restrict__ er,
    const float* __restrict__ h, const int* __restrict__ row,
    const int* __restrict__ srcs, float* __restrict__ rst, int n)
{
    const int wave = blockIdx.x * 4 + (threadIdx.x >> 6);
    const int lane = threadIdx.x & 63;
    if (wave >= n) return;
    const int d = wave;
    const int start = row[d], end = row[d + 1];
    const int hd0 = lane >> 4;
    const float er0 = er[(long long)d * 8 + hd0];
    const float er1 = er[(long long)d * 8 + hd0 + 4];

    float acc0 = 0.f, acc1 = 0.f, den0 = 0.f, den1 = 0.f;
    for (int p = start; p < end; ++p) {
        const int s = srcs[p];
        float e0 = el[(long long)s * 8 + hd0] + er0;
        float e1 = el[(long long)s * 8 + hd0 + 4] + er1;
        e0 = e0 >= 0.f ? e0 : NEG_SLOPE * e0;
        e1 = e1 >= 0.f ? e1 : NEG_SLOPE * e1;
        const float w0 = __expf(e0);
        const float w1 = __expf(e1);
        den0 += w0; den1 += w1;
        acc0 += w0 * h[(long long)s * 128 + lane];
        acc1 += w1 * h[(long long)s * 128 + 64 + lane];
    }
    const float r0 = (end > start) ? acc0 / den0 : 0.f;
    const float r1 = (end > start) ? acc1 / den1 : 0.f;
    rst[(long long)d * 128 + lane] = r0;
    rst[(long long)d * 128 + 64 + lane] = r1;
}

// ---------------------------------------------------------------------------
// K4: GCNII combine, K=256 (concat(rst+bias, h0)). 128-row tile, 8x8 acc,
// split cols. Epilogue re-reads rst/h0/input (LLC-warm, coalesced).
// ---------------------------------------------------------------------------
__global__ __launch_bounds__(256)
__attribute__((amdgpu_waves_per_eu(4, 4)))
void combine_gemm_kernel(
    const float* __restrict__ rst, const float* __restrict__ gat_bias,
    const float* __restrict__ h0, const float* __restrict__ input,
    const float* __restrict__ W, const int* __restrict__ l_p,
    const float* __restrict__ lamda_p, const float* __restrict__ alpha_p,
    float* __restrict__ x, int n)
{
    __shared__ float As[32][132];
    __shared__ float Bs[32][132];
    const int tid = threadIdx.x;
    const int tx = tid & 15;
    const int ty = tid >> 4;
    const int rowBase = blockIdx.x * 128;

    float acc[8][8];
#pragma unroll
    for (int i = 0; i < 8; ++i)
#pragma unroll
        for (int j = 0; j < 8; ++j) acc[i][j] = 0.f;

    for (int ci = 0; ci < 8; ++ci) {
        const int kc = ci * 32;
        const int koff = kc & 127;
        const bool first = ci < 4;
#pragma unroll
        for (int it = 0; it < 4; ++it) {
            const int flat = it * 256 + tid;
            const int r = flat >> 3;
            const int q = flat & 7;
            int row = rowBase + r;
            if (row >= n) row = n - 1;
            float4 v;
            if (first) {
                v = *(const float4*)&rst[(long long)row * 128 + koff + q * 4];
                const float4 b = *(const float4*)&gat_bias[koff + q * 4];
                v.x += b.x; v.y += b.y; v.z += b.z; v.w += b.w;
            } else {
                v = *(const float4*)&h0[(long long)row * 128 + koff + q * 4];
            }
            As[q * 4 + 0][r] = v.x;
            As[q * 4 + 1][r] = v.y;
            As[q * 4 + 2][r] = v.z;
            As[q * 4 + 3][r] = v.w;
        }
#pragma unroll
        for (int it = 0; it < 4; ++it) {
            const int flat = it * 256 + tid;
            const int k = flat >> 5;
            const int c4 = flat & 31;
            *(float4*)&Bs[k][c4 * 4] =
                *(const float4*)&W[(long long)(kc + k) * 128 + c4 * 4];
        }
        __syncthreads();

#pragma unroll
        for (int k = 0; k < 32; ++k) {
            const float4 a0 = *(const float4*)&As[k][ty * 8];
            const float4 a1 = *(const float4*)&As[k][ty * 8 + 4];
            const float4 b0 = *(const float4*)&Bs[k][tx * 4];
            const float4 b1 = *(const float4*)&Bs[k][64 + tx * 4];
            const float ar[8] = {a0.x, a0.y, a0.z, a0.w, a1.x, a1.y, a1.z, a1.w};
            const float br[8] = {b0.x, b0.y, b0.z, b0.w, b1.x, b1.y, b1.z, b1.w};
#pragma unroll
            for (int i = 0; i < 8; ++i)
#pragma unroll
                for (int j = 0; j < 8; ++j) acc[i][j] += ar[i] * br[j];
        }
        __syncthreads();
    }

    const float alpha = alpha_p[0];
    const float theta = fminf(1.0f, logf(lamda_p[0] / (float)l_p[0] + 1.0f));
    const float c1 = (1.f - theta) * (1.f - alpha);
    const float c2 = (1.f - theta) * alpha;
    const float4 bias0 = *(const float4*)&gat_bias[tx * 4];
    const float4 bias1 = *(const float4*)&gat_bias[64 + tx * 4];

#pragma unroll
    for (int i = 0; i < 8; ++i) {
        const int row = rowBase + ty * 8 + i;
        if (row >= n) break;
        const long long off = (long long)row * 128;
        const float4 rs0 = *(const float4*)&rst[off + tx * 4];
        const float4 rs1 = *(const float4*)&rst[off + 64 + tx * 4];
        const float4 h00 = *(const float4*)&h0[off + tx * 4];
        const float4 h01 = *(const float4*)&h0[off + 64 + tx * 4];
        const float4 in0 = *(const float4*)&input[off + tx * 4];
        const float4 in1 = *(const float4*)&input[off + 64 + tx * 4];
        float4 o0, o1;
        o0.x = theta * acc[i][0] + c1 * (rs0.x + bias0.x) + c2 * h00.x + in0.x;
        o0.y = theta * acc[i][1] + c1 * (rs0.y + bias0.y) + c2 * h00.y + in0.y;
        o0.z = theta * acc[i][2] + c1 * (rs0.z + bias0.z) + c2 * h00.z + in0.z;
        o0.w = theta * acc[i][3] + c1 * (rs0.w + bias0.w) + c2 * h00.w + in0.w;
        o1.x = theta * acc[i][4] + c1 * (rs1.x + bias1.x) + c2 * h01.x + in1.x;
        o1.y = theta * acc[i][5] + c1 * (rs1.y + bias1.y) + c2 * h01.y + in1.y;
        o1.z = theta * acc[i][6] + c1 * (rs1.z + bias1.z) + c2 * h01.z + in1.z;
        o1.w = theta * acc[i][7] + c1 * (rs1.w + bias1.w) + c2 * h01.w + in1.w;
        *(float4*)&x[off + tx * 4] = o0;
        *(float4*)&x[off + 64 + tx * 4] = o1;
    }
}

// ---------------------------------------------------------------------------
// K5: per-subgraph partial sums (split over nodes, atomics into (B,128)).
// ---------------------------------------------------------------------------
__global__ __launch_bounds__(128) void stats_kernel(
    const float* __restrict__ x, const int* __restrict__ cums,
    float* __restrict__ sums, float* __restrict__ sumsq)
{
    const int b = blockIdx.x / STATS_SPLIT;
    const int part = blockIdx.x % STATS_SPLIT;
    const int tid = threadIdx.x;
    const int start = cums[b], end = cums[b + 1];
    float s = 0.f, s2 = 0.f;
    for (int node = start + part; node < end; node += STATS_SPLIT) {
        const float v = x[(long long)node * 128 + tid];
        s += v;
        s2 += v * v;
    }
    atomicAdd(&sums[b * 128 + tid], s);
    atomicAdd(&sumsq[b * 128 + tid], s2);
}

__global__ __launch_bounds__(128) void finalize_stats_kernel(
    const int* __restrict__ cums, float* __restrict__ sums,
    float* __restrict__ sumsq)
{
    const int b = blockIdx.x;
    const int tid = threadIdx.x;
    const float cnt = (float)(cums[b + 1] - cums[b]);
    const float s = sums[b * 128 + tid];
    const float s2 = sumsq[b * 128 + tid];
    const float mean = s / cnt;
    float var = (s2 - s * mean) / (cnt - 1.f);
    var = fmaxf(var, 0.f);
    sums[b * 128 + tid] = mean;
    sumsq[b * 128 + tid] = 1.f / (sqrtf(var) + 1e-5f);
}

__global__ __launch_bounds__(256) void norm_kernel(
    const float* __restrict__ x, const float* __restrict__ mean,
    const float* __restrict__ istd, const int* __restrict__ cums, int nb,
    const float* __restrict__ gamma, const float* __restrict__ beta,
    float* __restrict__ out, int n)
{
    const long long gid = (long long)blockIdx.x * 256 + threadIdx.x;
    const int node = (int)(gid >> 5);
    if (node >= n) return;
    const int f4 = (int)(gid & 31);
    int lo = 0, hi = nb;
    while (hi - lo > 1) {
        const int mid = (lo + hi) >> 1;
        if (cums[mid] <= node) lo = mid; else hi = mid;
    }
    const float4 m = *(const float4*)&mean[lo * 128 + f4 * 4];
    const float4 is = *(const float4*)&istd[lo * 128 + f4 * 4];
    const float4 g = *(const float4*)&gamma[f4 * 4];
    const float4 bt = *(const float4*)&beta[f4 * 4];
    const float4 v = *(const float4*)&x[(long long)node * 128 + f4 * 4];
    float4 o;
    o.x = g.x * ((v.x - m.x) * is.x) + bt.x;
    o.y = g.y * ((v.y - m.y) * is.y) + bt.y;
    o.z = g.z * ((v.z - m.z) * is.z) + bt.z;
    o.w = g.w * ((v.w - m.w) * is.w) + bt.w;
    *(float4*)&out[(long long)node * 128 + f4 * 4] = o;
}

// ---------------------------------------------------------------------------
extern "C" void kernel_launch(void* const* d_in, const int* in_sizes, int n_in,
                              void* d_out, int out_size, void* d_ws, size_t ws_size,
                              hipStream_t stream) {
    const float* input   = (const float*)d_in[0];
    const float* h0      = (const float*)d_in[1];
    const int*   src     = (const int*)d_in[2];
    const int*   dst     = (const int*)d_in[3];
    const int*   cums    = (const int*)d_in[4];
    const int*   l_p     = (const int*)d_in[5];
    const float* lamda_p = (const float*)d_in[6];
    const float* alpha_p = (const float*)d_in[7];
    const float* W_fc    = (const float*)d_in[8];
    const float* attn_l  = (const float*)d_in[9];
    const float* attn_r  = (const float*)d_in[10];
    const float* gat_bias= (const float*)d_in[11];
    const float* W_comb  = (const float*)d_in[12];
    const float* gamma   = (const float*)d_in[13];
    const float* beta    = (const float*)d_in[14];

    const int n  = in_sizes[0] / 128;
    const int E  = in_sizes[2];
    const int nb = in_sizes[4] - 1;
    float* out = (float*)d_out;

    // workspace layout
    char* ws = (char*)d_ws;
    size_t o = 0;
    float* h        = (float*)(ws + o); o += (size_t)n * 128 * 4;
    float* el       = (float*)(ws + o); o += (size_t)n * 8 * 4;
    float* er       = (float*)(ws + o); o += (size_t)n * 8 * 4;
    float* rst      = (float*)(ws + o); o += (size_t)n * 128 * 4;
    float* sums     = (float*)(ws + o); o += (size_t)nb * 128 * 4;
    float* sumsq    = (float*)(ws + o); o += (size_t)nb * 128 * 4;
    int* deg        = (int*)(ws + o);   o += (size_t)n * 4;
    int* row_ptr    = (int*)(ws + o);   o += (size_t)(n + 1) * 4;
    int* cursor     = (int*)(ws + o);   o += (size_t)n * 4;
    int* blockSums  = (int*)(ws + o);   o += 128 * 4;
    int* srcs       = (int*)(ws + o);   o += (size_t)E * 4;

    hipMemsetAsync(deg, 0, (size_t)n * 4, stream);
    hipMemsetAsync(sums, 0, (size_t)nb * 128 * 4 * 2, stream);

    // --- CSR build ---
    hist_kernel<<<(E + 255) / 256, 256, 0, stream>>>(dst, deg, E);
    const int nblk1 = (n + 1023) / 1024;
    scan1_kernel<<<nblk1, 256, 0, stream>>>(deg, row_ptr, blockSums, n);
    scan2_kernel<<<1, 128, 0, stream>>>(blockSums, nblk1);
    scan3_kernel<<<(n + 255) / 256, 256, 0, stream>>>(row_ptr, cursor, blockSums, n, E);
    scatter_kernel<<<(E + 255) / 256, 256, 0, stream>>>(src, dst, cursor, srcs, E);

    // --- dense pipeline ---
    const int gemm_grid = (n + 127) / 128;
    fc_gemm_kernel<<<gemm_grid, 256, 0, stream>>>(
        input, W_fc, attn_l, attn_r, h, el, er, n);

    aggregate_kernel<<<(n + 3) / 4, 256, 0, stream>>>(
        el, er, h, row_ptr, srcs, rst, n);

    combine_gemm_kernel<<<gemm_grid, 256, 0, stream>>>(
        rst, gat_bias, h0, input, W_comb, l_p, lamda_p, alpha_p, out, n);

    stats_kernel<<<nb * STATS_SPLIT, 128, 0, stream>>>(out, cums, sums, sumsq);
    finalize_stats_kernel<<<nb, 128, 0, stream>>>(cums, sums, sumsq);

    const long long norm_threads = (long long)n * 32;
    norm_kernel<<<(int)((norm_threads + 255) / 256), 256, 0, stream>>>(
        out, sums, sumsq, cums, nb, gamma, beta, out, n);
}

// Round 6
// 355.159 us; speedup vs baseline: 2.9486x; 1.2321x over previous
//
#include <hip/hip_runtime.h>
#include <hip/hip_bf16.h>

#define NEG_SLOPE 0.2f
#define STATS_SPLIT 50

// ---------------------------------------------------------------------------
// K1: h = input @ W_fc  (N x 128) @ (128 x 128), fused el/er epilogue.
// 64-row tile, 256 threads, 4x8 acc/thread (32 acc VGPRs -> no spill),
// split cols (tx*4 and 64+tx*4) -> 16B-stride LDS reads (2-way alias, free).
// Grid = N/64 = 1563 blocks = 6.1 WG/CU.
// ---------------------------------------------------------------------------
__global__ __launch_bounds__(256) void fc_gemm_kernel(
    const float* __restrict__ A, const float* __restrict__ W,
    const float* __restrict__ attn_l, const float* __restrict__ attn_r,
    float* __restrict__ h, float* __restrict__ el, float* __restrict__ er,
    int n)
{
    __shared__ float As[32][68];   // k-major: As[k][row]
    __shared__ float Bs[32][132];  // k-major: Bs[k][col]
    const int tid = threadIdx.x;
    const int tx = tid & 15;       // col quads: tx*4 and 64+tx*4
    const int ty = tid >> 4;       // rows ty*4 .. ty*4+3
    const int rowBase = blockIdx.x * 64;

    float acc[4][8];
#pragma unroll
    for (int i = 0; i < 4; ++i)
#pragma unroll
        for (int j = 0; j < 8; ++j) acc[i][j] = 0.f;

    for (int ci = 0; ci < 4; ++ci) {
        const int kc = ci * 32;
        // stage A: 64 rows x 32 k (512 float4, 2/thread), transposed store
#pragma unroll
        for (int it = 0; it < 2; ++it) {
            const int flat = it * 256 + tid;
            const int q = flat & 7;        // k-quad
            const int r = flat >> 3;       // row 0..63
            int row = rowBase + r;
            if (row >= n) row = n - 1;
            const float4 v = *(const float4*)&A[(long long)row * 128 + kc + q * 4];
            As[q * 4 + 0][r] = v.x;
            As[q * 4 + 1][r] = v.y;
            As[q * 4 + 2][r] = v.z;
            As[q * 4 + 3][r] = v.w;
        }
        // stage B: 32 k x 128 cols (1024 float4, 4/thread)
#pragma unroll
        for (int it = 0; it < 4; ++it) {
            const int flat = it * 256 + tid;
            const int k = flat >> 5;
            const int c4 = flat & 31;
            *(float4*)&Bs[k][c4 * 4] =
                *(const float4*)&W[(long long)(kc + k) * 128 + c4 * 4];
        }
        __syncthreads();

#pragma unroll
        for (int k = 0; k < 32; ++k) {
            const float4 a  = *(const float4*)&As[k][ty * 4];
            const float4 b0 = *(const float4*)&Bs[k][tx * 4];
            const float4 b1 = *(const float4*)&Bs[k][64 + tx * 4];
            const float ar[4] = {a.x, a.y, a.z, a.w};
            const float br[8] = {b0.x, b0.y, b0.z, b0.w, b1.x, b1.y, b1.z, b1.w};
#pragma unroll
            for (int i = 0; i < 4; ++i)
#pragma unroll
                for (int j = 0; j < 8; ++j) acc[i][j] += ar[i] * br[j];
        }
        __syncthreads();
    }

    // epilogue: write h + fused el/er.
    // group A cols tx*4.. -> head tx>>2; group B cols 64+tx*4.. -> head 4+(tx>>2)
    const float4 alA = *(const float4*)&attn_l[tx * 4];
    const float4 alB = *(const float4*)&attn_l[64 + tx * 4];
    const float4 arA = *(const float4*)&attn_r[tx * 4];
    const float4 arB = *(const float4*)&attn_r[64 + tx * 4];
#pragma unroll
    for (int i = 0; i < 4; ++i) {
        const int row = rowBase + ty * 4 + i;
        if (row >= n) break;
        const long long off = (long long)row * 128;
        float4 o0 = {acc[i][0], acc[i][1], acc[i][2], acc[i][3]};
        float4 o1 = {acc[i][4], acc[i][5], acc[i][6], acc[i][7]};
        *(float4*)&h[off + tx * 4] = o0;
        *(float4*)&h[off + 64 + tx * 4] = o1;
        float l0 = o0.x * alA.x + o0.y * alA.y + o0.z * alA.z + o0.w * alA.w;
        float l1 = o1.x * alB.x + o1.y * alB.y + o1.z * alB.z + o1.w * alB.w;
        float r0 = o0.x * arA.x + o0.y * arA.y + o0.z * arA.z + o0.w * arA.w;
        float r1 = o1.x * arB.x + o1.y * arB.y + o1.z * arB.z + o1.w * arB.w;
#pragma unroll
        for (int offx = 1; offx <= 2; offx <<= 1) {
            l0 += __shfl_xor(l0, offx, 64);
            l1 += __shfl_xor(l1, offx, 64);
            r0 += __shfl_xor(r0, offx, 64);
            r1 += __shfl_xor(r1, offx, 64);
        }
        if ((tx & 3) == 0) {
            const int hd = tx >> 2;
            el[(long long)row * 8 + hd] = l0;
            el[(long long)row * 8 + 4 + hd] = l1;
            er[(long long)row * 8 + hd] = r0;
            er[(long long)row * 8 + 4 + hd] = r1;
        }
    }
}

// ---------------------------------------------------------------------------
// CSR build: histogram -> 2-level exclusive scan -> scatter src ids by dst.
// ---------------------------------------------------------------------------
__global__ __launch_bounds__(256) void hist_kernel(
    const int* __restrict__ dst, int* __restrict__ deg, int E)
{
    const int i = blockIdx.x * 256 + threadIdx.x;
    if (i < E) atomicAdd(&deg[dst[i]], 1);
}

__global__ __launch_bounds__(256) void scan1_kernel(
    const int* __restrict__ deg, int* __restrict__ row,
    int* __restrict__ blockSums, int n)
{
    __shared__ int sdata[256];
    const int t = threadIdx.x;
    const int base = blockIdx.x * 1024 + t * 4;
    int v[4];
    int tot = 0;
#pragma unroll
    for (int j = 0; j < 4; ++j) {
        v[j] = (base + j < n) ? deg[base + j] : 0;
        tot += v[j];
    }
    sdata[t] = tot;
    __syncthreads();
    for (int off = 1; off < 256; off <<= 1) {
        const int x = (t >= off) ? sdata[t - off] : 0;
        __syncthreads();
        sdata[t] += x;
        __syncthreads();
    }
    if (t == 255) blockSums[blockIdx.x] = sdata[255];
    int run = sdata[t] - tot;
#pragma unroll
    for (int j = 0; j < 4; ++j) {
        if (base + j < n) row[base + j] = run;
        run += v[j];
    }
}

__global__ __launch_bounds__(128) void scan2_kernel(
    int* __restrict__ blockSums, int nb)
{
    __shared__ int sdata[128];
    const int t = threadIdx.x;
    const int v = (t < nb) ? blockSums[t] : 0;
    sdata[t] = v;
    __syncthreads();
    for (int off = 1; off < 128; off <<= 1) {
        const int x = (t >= off) ? sdata[t - off] : 0;
        __syncthreads();
        sdata[t] += x;
        __syncthreads();
    }
    if (t < nb) blockSums[t] = sdata[t] - v;
}

__global__ __launch_bounds__(256) void scan3_kernel(
    int* __restrict__ row, int* __restrict__ cursor,
    const int* __restrict__ blockSums, int n, int E)
{
    const int i = blockIdx.x * 256 + threadIdx.x;
    if (i == 0) row[n] = E;
    if (i >= n) return;
    const int r = row[i] + blockSums[i >> 10];
    row[i] = r;
    cursor[i] = r;
}

__global__ __launch_bounds__(256) void scatter_kernel(
    const int* __restrict__ src, const int* __restrict__ dst,
    int* __restrict__ cursor, int* __restrict__ srcs, int E)
{
    const int i = blockIdx.x * 256 + threadIdx.x;
    if (i >= E) return;
    const int pos = atomicAdd(&cursor[dst[i]], 1);
    srcs[pos] = src[i];
}

// ---------------------------------------------------------------------------
// K3: aggregate. One wave per dst node, 2 features/lane, local softmax,
// no atomics.
// ---------------------------------------------------------------------------
__global__ __launch_bounds__(256) void aggregate_kernel(
    const float* __restrict__ el, const float* __restrict__ er,
    const float* __restrict__ h, const int* __restrict__ row,
    const int* __restrict__ srcs, float* __restrict__ rst, int n)
{
    const int wave = blockIdx.x * 4 + (threadIdx.x >> 6);
    const int lane = threadIdx.x & 63;
    if (wave >= n) return;
    const int d = wave;
    const int start = row[d], end = row[d + 1];
    const int hd0 = lane >> 4;
    const float er0 = er[(long long)d * 8 + hd0];
    const float er1 = er[(long long)d * 8 + hd0 + 4];

    float acc0 = 0.f, acc1 = 0.f, den0 = 0.f, den1 = 0.f;
    for (int p = start; p < end; ++p) {
        const int s = srcs[p];
        float e0 = el[(long long)s * 8 + hd0] + er0;
        float e1 = el[(long long)s * 8 + hd0 + 4] + er1;
        e0 = e0 >= 0.f ? e0 : NEG_SLOPE * e0;
        e1 = e1 >= 0.f ? e1 : NEG_SLOPE * e1;
        const float w0 = __expf(e0);
        const float w1 = __expf(e1);
        den0 += w0; den1 += w1;
        acc0 += w0 * h[(long long)s * 128 + lane];
        acc1 += w1 * h[(long long)s * 128 + 64 + lane];
    }
    const float r0 = (end > start) ? acc0 / den0 : 0.f;
    const float r1 = (end > start) ? acc1 / den1 : 0.f;
    rst[(long long)d * 128 + lane] = r0;
    rst[(long long)d * 128 + 64 + lane] = r1;
}

// ---------------------------------------------------------------------------
// K4: GCNII combine, K=256 (concat(rst+bias, h0)). 64-row tile, 4x8 acc,
// split cols. Epilogue re-reads rst/h0/input (L2/LLC-warm, coalesced).
// ---------------------------------------------------------------------------
__global__ __launch_bounds__(256) void combine_gemm_kernel(
    const float* __restrict__ rst, const float* __restrict__ gat_bias,
    const float* __restrict__ h0, const float* __restrict__ input,
    const float* __restrict__ W, const int* __restrict__ l_p,
    const float* __restrict__ lamda_p, const float* __restrict__ alpha_p,
    float* __restrict__ x, int n)
{
    __shared__ float As[32][68];
    __shared__ float Bs[32][132];
    const int tid = threadIdx.x;
    const int tx = tid & 15;
    const int ty = tid >> 4;
    const int rowBase = blockIdx.x * 64;

    float acc[4][8];
#pragma unroll
    for (int i = 0; i < 4; ++i)
#pragma unroll
        for (int j = 0; j < 8; ++j) acc[i][j] = 0.f;

    for (int ci = 0; ci < 8; ++ci) {
        const int kc = ci * 32;
        const int koff = kc & 127;
        const bool first = ci < 4;
        // stage A: 64 rows x 32 k (512 float4, 2/thread)
#pragma unroll
        for (int it = 0; it < 2; ++it) {
            const int flat = it * 256 + tid;
            const int q = flat & 7;
            const int r = flat >> 3;
            int row = rowBase + r;
            if (row >= n) row = n - 1;
            float4 v;
            if (first) {
                v = *(const float4*)&rst[(long long)row * 128 + koff + q * 4];
                const float4 b = *(const float4*)&gat_bias[koff + q * 4];
                v.x += b.x; v.y += b.y; v.z += b.z; v.w += b.w;
            } else {
                v = *(const float4*)&h0[(long long)row * 128 + koff + q * 4];
            }
            As[q * 4 + 0][r] = v.x;
            As[q * 4 + 1][r] = v.y;
            As[q * 4 + 2][r] = v.z;
            As[q * 4 + 3][r] = v.w;
        }
        // stage B
#pragma unroll
        for (int it = 0; it < 4; ++it) {
            const int flat = it * 256 + tid;
            const int k = flat >> 5;
            const int c4 = flat & 31;
            *(float4*)&Bs[k][c4 * 4] =
                *(const float4*)&W[(long long)(kc + k) * 128 + c4 * 4];
        }
        __syncthreads();

#pragma unroll
        for (int k = 0; k < 32; ++k) {
            const float4 a  = *(const float4*)&As[k][ty * 4];
            const float4 b0 = *(const float4*)&Bs[k][tx * 4];
            const float4 b1 = *(const float4*)&Bs[k][64 + tx * 4];
            const float ar[4] = {a.x, a.y, a.z, a.w};
            const float br[8] = {b0.x, b0.y, b0.z, b0.w, b1.x, b1.y, b1.z, b1.w};
#pragma unroll
            for (int i = 0; i < 4; ++i)
#pragma unroll
                for (int j = 0; j < 8; ++j) acc[i][j] += ar[i] * br[j];
        }
        __syncthreads();
    }

    const float alpha = alpha_p[0];
    const float theta = fminf(1.0f, logf(lamda_p[0] / (float)l_p[0] + 1.0f));
    const float c1 = (1.f - theta) * (1.f - alpha);
    const float c2 = (1.f - theta) * alpha;
    const float4 bias0 = *(const float4*)&gat_bias[tx * 4];
    const float4 bias1 = *(const float4*)&gat_bias[64 + tx * 4];

#pragma unroll
    for (int i = 0; i < 4; ++i) {
        const int row = rowBase + ty * 4 + i;
        if (row >= n) break;
        const long long off = (long long)row * 128;
        const float4 rs0 = *(const float4*)&rst[off + tx * 4];
        const float4 rs1 = *(const float4*)&rst[off + 64 + tx * 4];
        const float4 h00 = *(const float4*)&h0[off + tx * 4];
        const float4 h01 = *(const float4*)&h0[off + 64 + tx * 4];
        const float4 in0 = *(const float4*)&input[off + tx * 4];
        const float4 in1 = *(const float4*)&input[off + 64 + tx * 4];
        float4 o0, o1;
        o0.x = theta * acc[i][0] + c1 * (rs0.x + bias0.x) + c2 * h00.x + in0.x;
        o0.y = theta * acc[i][1] + c1 * (rs0.y + bias0.y) + c2 * h00.y + in0.y;
        o0.z = theta * acc[i][2] + c1 * (rs0.z + bias0.z) + c2 * h00.z + in0.z;
        o0.w = theta * acc[i][3] + c1 * (rs0.w + bias0.w) + c2 * h00.w + in0.w;
        o1.x = theta * acc[i][4] + c1 * (rs1.x + bias1.x) + c2 * h01.x + in1.x;
        o1.y = theta * acc[i][5] + c1 * (rs1.y + bias1.y) + c2 * h01.y + in1.y;
        o1.z = theta * acc[i][6] + c1 * (rs1.z + bias1.z) + c2 * h01.z + in1.z;
        o1.w = theta * acc[i][7] + c1 * (rs1.w + bias1.w) + c2 * h01.w + in1.w;
        *(float4*)&x[off + tx * 4] = o0;
        *(float4*)&x[off + 64 + tx * 4] = o1;
    }
}

// ---------------------------------------------------------------------------
// K5: per-subgraph partial sums (split over nodes, atomics into (B,128)).
// ---------------------------------------------------------------------------
__global__ __launch_bounds__(128) void stats_kernel(
    const float* __restrict__ x, const int* __restrict__ cums,
    float* __restrict__ sums, float* __restrict__ sumsq)
{
    const int b = blockIdx.x / STATS_SPLIT;
    const int part = blockIdx.x % STATS_SPLIT;
    const int tid = threadIdx.x;
    const int start = cums[b], end = cums[b + 1];
    float s = 0.f, s2 = 0.f;
    for (int node = start + part; node < end; node += STATS_SPLIT) {
        const float v = x[(long long)node * 128 + tid];
        s += v;
        s2 += v * v;
    }
    atomicAdd(&sums[b * 128 + tid], s);
    atomicAdd(&sumsq[b * 128 + tid], s2);
}

__global__ __launch_bounds__(128) void finalize_stats_kernel(
    const int* __restrict__ cums, float* __restrict__ sums,
    float* __restrict__ sumsq)
{
    const int b = blockIdx.x;
    const int tid = threadIdx.x;
    const float cnt = (float)(cums[b + 1] - cums[b]);
    const float s = sums[b * 128 + tid];
    const float s2 = sumsq[b * 128 + tid];
    const float mean = s / cnt;
    float var = (s2 - s * mean) / (cnt - 1.f);
    var = fmaxf(var, 0.f);
    sums[b * 128 + tid] = mean;
    sumsq[b * 128 + tid] = 1.f / (sqrtf(var) + 1e-5f);
}

__global__ __launch_bounds__(256) void norm_kernel(
    const float* __restrict__ x, const float* __restrict__ mean,
    const float* __restrict__ istd, const int* __restrict__ cums, int nb,
    const float* __restrict__ gamma, const float* __restrict__ beta,
    float* __restrict__ out, int n)
{
    const long long gid = (long long)blockIdx.x * 256 + threadIdx.x;
    const int node = (int)(gid >> 5);
    if (node >= n) return;
    const int f4 = (int)(gid & 31);
    int lo = 0, hi = nb;
    while (hi - lo > 1) {
        const int mid = (lo + hi) >> 1;
        if (cums[mid] <= node) lo = mid; else hi = mid;
    }
    const float4 m = *(const float4*)&mean[lo * 128 + f4 * 4];
    const float4 is = *(const float4*)&istd[lo * 128 + f4 * 4];
    const float4 g = *(const float4*)&gamma[f4 * 4];
    const float4 bt = *(const float4*)&beta[f4 * 4];
    const float4 v = *(const float4*)&x[(long long)node * 128 + f4 * 4];
    float4 o;
    o.x = g.x * ((v.x - m.x) * is.x) + bt.x;
    o.y = g.y * ((v.y - m.y) * is.y) + bt.y;
    o.z = g.z * ((v.z - m.z) * is.z) + bt.z;
    o.w = g.w * ((v.w - m.w) * is.w) + bt.w;
    *(float4*)&out[(long long)node * 128 + f4 * 4] = o;
}

// ---------------------------------------------------------------------------
extern "C" void kernel_launch(void* const* d_in, const int* in_sizes, int n_in,
                              void* d_out, int out_size, void* d_ws, size_t ws_size,
                              hipStream_t stream) {
    const float* input   = (const float*)d_in[0];
    const float* h0      = (const float*)d_in[1];
    const int*   src     = (const int*)d_in[2];
    const int*   dst     = (const int*)d_in[3];
    const int*   cums    = (const int*)d_in[4];
    const int*   l_p     = (const int*)d_in[5];
    const float* lamda_p = (const float*)d_in[6];
    const float* alpha_p = (const float*)d_in[7];
    const float* W_fc    = (const float*)d_in[8];
    const float* attn_l  = (const float*)d_in[9];
    const float* attn_r  = (const float*)d_in[10];
    const float* gat_bias= (const float*)d_in[11];
    const float* W_comb  = (const float*)d_in[12];
    const float* gamma   = (const float*)d_in[13];
    const float* beta    = (const float*)d_in[14];

    const int n  = in_sizes[0] / 128;
    const int E  = in_sizes[2];
    const int nb = in_sizes[4] - 1;
    float* out = (float*)d_out;

    // workspace layout
    char* ws = (char*)d_ws;
    size_t o = 0;
    float* h        = (float*)(ws + o); o += (size_t)n * 128 * 4;
    float* el       = (float*)(ws + o); o += (size_t)n * 8 * 4;
    float* er       = (float*)(ws + o); o += (size_t)n * 8 * 4;
    float* rst      = (float*)(ws + o); o += (size_t)n * 128 * 4;
    float* sums     = (float*)(ws + o); o += (size_t)nb * 128 * 4;
    float* sumsq    = (float*)(ws + o); o += (size_t)nb * 128 * 4;
    int* deg        = (int*)(ws + o);   o += (size_t)n * 4;
    int* row_ptr    = (int*)(ws + o);   o += (size_t)(n + 1) * 4;
    int* cursor     = (int*)(ws + o);   o += (size_t)n * 4;
    int* blockSums  = (int*)(ws + o);   o += 128 * 4;
    int* srcs       = (int*)(ws + o);   o += (size_t)E * 4;

    hipMemsetAsync(deg, 0, (size_t)n * 4, stream);
    hipMemsetAsync(sums, 0, (size_t)nb * 128 * 4 * 2, stream);

    // --- CSR build ---
    hist_kernel<<<(E + 255) / 256, 256, 0, stream>>>(dst, deg, E);
    const int nblk1 = (n + 1023) / 1024;
    scan1_kernel<<<nblk1, 256, 0, stream>>>(deg, row_ptr, blockSums, n);
    scan2_kernel<<<1, 128, 0, stream>>>(blockSums, nblk1);
    scan3_kernel<<<(n + 255) / 256, 256, 0, stream>>>(row_ptr, cursor, blockSums, n, E);
    scatter_kernel<<<(E + 255) / 256, 256, 0, stream>>>(src, dst, cursor, srcs, E);

    // --- dense pipeline ---
    const int gemm_grid = (n + 63) / 64;
    fc_gemm_kernel<<<gemm_grid, 256, 0, stream>>>(
        input, W_fc, attn_l, attn_r, h, el, er, n);

    aggregate_kernel<<<(n + 3) / 4, 256, 0, stream>>>(
        el, er, h, row_ptr, srcs, rst, n);

    combine_gemm_kernel<<<gemm_grid, 256, 0, stream>>>(
        rst, gat_bias, h0, input, W_comb, l_p, lamda_p, alpha_p, out, n);

    stats_kernel<<<nb * STATS_SPLIT, 128, 0, stream>>>(out, cums, sums, sumsq);
    finalize_stats_kernel<<<nb, 128, 0, stream>>>(cums, sums, sumsq);

    const long long norm_threads = (long long)n * 32;
    norm_kernel<<<(int)((norm_threads + 255) / 256), 256, 0, stream>>>(
        out, sums, sumsq, cums, nb, gamma, beta, out, n);
}